// Round 22
// baseline (1287.977 us; speedup 1.0000x reference)
//
#include <hip/hip_runtime.h>
#include <math.h>

#define NN 100000
#define NN2 200000
#define NE 1200000
#define EMBD 100
#define HD 64
#define BT 4096
#define SCAN_B 196     // 196 * 1024 >= NN2
#define HIST_B 9375    // 2*NE / 256
#define EMB_B 12500    // NN2 / 16

typedef __attribute__((ext_vector_type(8))) short short8;  // 8 bf16 (4 VGPRs)
typedef __attribute__((ext_vector_type(4))) float f32x4;   // MFMA C/D
typedef __attribute__((ext_vector_type(2))) float f32x2;   // fp8 pk-cvt result

__device__ __forceinline__ float sig1(float x) { return 1.f / (1.f + __expf(-x)); }
__device__ __forceinline__ float tanh1(float x) {
    x = fminf(fmaxf(x, -15.f), 15.f);
    float e = __expf(2.f * x);
    return (e - 1.f) / (e + 1.f);
}
__device__ __forceinline__ unsigned short f2b(float f) {
    unsigned u = __float_as_uint(f);
    u += 0x7fffu + ((u >> 16) & 1u);
    return (unsigned short)(u >> 16);
}
__device__ __forceinline__ unsigned short hi16(float f) {  // exact for fp8-sourced values
    return (unsigned short)(__float_as_uint(f) >> 16);
}
__device__ __forceinline__ unsigned packb(float lo, float hi) {
    return (unsigned)f2b(lo) | ((unsigned)f2b(hi) << 16);
}
// PERMUTED row layout for hb8 (fp8 state) and aggb rows: position p holds feature
// (p&3)*16 + (p>>2); feature f lives at p = 4*(f&15) + (f>>4). Baked into wpack.
__device__ __forceinline__ unsigned pk8(float a, float b, float c, float d) {
    int w = 0;
    w = __builtin_amdgcn_cvt_pk_fp8_f32(a, b, w, false);
    w = __builtin_amdgcn_cvt_pk_fp8_f32(c, d, w, true);
    return (unsigned)w;
}
// 8 fp8 bytes -> 8 bf16 (exact: every e4m3 value is bf16-representable)
__device__ __forceinline__ short8 f8frag(uint2 u) {
    const f32x2 a0 = __builtin_amdgcn_cvt_pk_f32_fp8(u.x, false);
    const f32x2 a1 = __builtin_amdgcn_cvt_pk_f32_fp8(u.x, true);
    const f32x2 a2 = __builtin_amdgcn_cvt_pk_f32_fp8(u.y, false);
    const f32x2 a3 = __builtin_amdgcn_cvt_pk_f32_fp8(u.y, true);
    short8 r;
    r[0] = (short)hi16(a0.x); r[1] = (short)hi16(a0.y);
    r[2] = (short)hi16(a1.x); r[3] = (short)hi16(a1.y);
    r[4] = (short)hi16(a2.x); r[5] = (short)hi16(a2.y);
    r[6] = (short)hi16(a3.x); r[7] = (short)hi16(a3.y);
    return r;
}

// ---- precompute Wf[l] = Wm[l] @ Wih[l] (64x192), bf[l] = bm[l] @ Wih[l] (192) ----
__global__ __launch_bounds__(256) void fusew_kernel(
    const float* __restrict__ Wm0, const float* __restrict__ Wih0, const float* __restrict__ bm0,
    const float* __restrict__ Wm1, const float* __restrict__ Wih1, const float* __restrict__ bm1,
    float* __restrict__ Wf, float* __restrict__ bf) {
    extern __shared__ float lds[];
    float* wm_s = lds;          // 4096
    float* wih_s = lds + 4096;  // 12288
    const int l = blockIdx.x >> 3, slice = blockIdx.x & 7;
    const float* Wm = l ? Wm1 : Wm0;
    const float* Wih = l ? Wih1 : Wih0;
    const float* bm = l ? bm1 : bm0;
    for (int i = threadIdx.x; i < 4096; i += 256) wm_s[i] = Wm[i];
    for (int i = threadIdx.x; i < 12288; i += 256) wih_s[i] = Wih[i];
    __syncthreads();
    float* Wfl = Wf + l * 12288;
    float* bfl = bf + l * 192;
    const int o0 = slice * 1536;
    for (int o = o0 + threadIdx.x; o < o0 + 1536; o += 256) {
        int r = o / 192, c = o % 192;
        float s = 0.f;
        for (int k = 0; k < 64; ++k) s = fmaf(wm_s[r * 64 + k], wih_s[k * 192 + c], s);
        Wfl[o] = s;
    }
    const int c0 = slice * 24;
    for (int c = c0 + threadIdx.x; c < c0 + 24; c += 256) {
        float s = 0.f;
        for (int k = 0; k < 64; ++k) s = fmaf(bm[k], wih_s[k * 192 + c], s);
        bfl[c] = s;
    }
}

// ---- pack W' (128x256) into MFMA B-fragment order, bf16. Both halves permuted rows. ----
__global__ __launch_bounds__(64) void wpack_kernel(
    const float* __restrict__ Wf, const float* __restrict__ Whh0, const float* __restrict__ Whh1,
    unsigned short* __restrict__ Wpk) {
    const int b = blockIdx.x;  // 0..127
    const int l = b >> 6, frag = b & 63;
    const int nt = frag >> 2, kk = frag & 3;
    const int lane = threadIdx.x;
    const int n = nt * 16 + (lane & 15);
    const int g = n >> 6, j = n & 63;
    const int k0 = kk * 32 + (lane >> 4) * 8;
    const float* wf = Wf + l * 12288;
    const float* whh = l ? Whh1 : Whh0;
    unsigned short o[8];
#pragma unroll
    for (int jj = 0; jj < 8; ++jj) {
        const int k = k0 + jj;
        float v = 0.f;
        if (k < 64) {
            const int kp = (k & 3) * 16 + (k >> 2);
            if (g == 0) v = wf[kp * 192 + j];
            else if (g == 1) v = wf[kp * 192 + 64 + j];
            else if (g == 2) v = wf[kp * 192 + 128 + j];
        } else {
            const int kp = ((k - 64) & 3) * 16 + ((k - 64) >> 2);
            if (g == 0) v = whh[kp * 192 + j];
            else if (g == 1) v = whh[kp * 192 + 64 + j];
            else if (g == 3) v = whh[kp * 192 + 128 + j];
        }
        o[jj] = f2b(v);
    }
    *(uint4*)(Wpk + ((size_t)(l * 64 + frag) * 64 + lane) * 8) = *(const uint4*)o;
}

// ---- FUSED hist + embed: independent work overlapped in one dispatch.
// Blocks [0, HIST_B): degree histogram. Blocks [HIST_B, HIST_B+EMB_B): embedding.
__global__ __launch_bounds__(256) void histembed_kernel(
    const int* __restrict__ adj0, const int* __restrict__ adj1, int* __restrict__ rowptr,
    const int* __restrict__ ind0, const int* __restrict__ ind1, const float* __restrict__ emb,
    const float* __restrict__ Wp, const float* __restrict__ bp, unsigned char* __restrict__ hb8) {
    if (blockIdx.x < HIST_B) {
        const int e = blockIdx.x * 256 + threadIdx.x;
        const int tgt = (e < NE) ? adj0[2 * e + 1] : adj1[2 * (e - NE) + 1] + NN;
        atomicAdd(&rowptr[tgt], 1);
        return;
    }
    __shared__ float et[4][EMBD][4];  // [wave][k][node]
    const int w = threadIdx.x >> 6;
    const int l = threadIdx.x & 63;
    const int nodeBase = (blockIdx.x - HIST_B) * 16 + w * 4;  // graph-pure per block
    for (int f = l; f < 100; f += 64) {
        const int n = f / 25, c = f % 25;
        const int gn = nodeBase + n;
        const int idx = (gn < NN) ? ind0[gn] : ind1[gn - NN];
        const float4 v = *(const float4*)(emb + (size_t)idx * EMBD + c * 4);
        et[w][c * 4 + 0][n] = v.x;
        et[w][c * 4 + 1][n] = v.y;
        et[w][c * 4 + 2][n] = v.z;
        et[w][c * 4 + 3][n] = v.w;
    }
    __syncthreads();
    float acc[4];
    acc[0] = bp[l]; acc[1] = acc[0]; acc[2] = acc[0]; acc[3] = acc[0];
#pragma unroll 5
    for (int k = 0; k < EMBD; ++k) {
        const float wv = Wp[k * 64 + l];
        const float4 ev = *(const float4*)&et[w][k][0];
        acc[0] = fmaf(ev.x, wv, acc[0]);
        acc[1] = fmaf(ev.y, wv, acc[1]);
        acc[2] = fmaf(ev.z, wv, acc[2]);
        acc[3] = fmaf(ev.w, wv, acc[3]);
    }
#pragma unroll
    for (int n = 0; n < 4; ++n) {
        const float v0 = __shfl(acc[n], l & 15);
        const float v1 = __shfl(acc[n], (l & 15) + 16);
        const float v2 = __shfl(acc[n], (l & 15) + 32);
        const float v3 = __shfl(acc[n], (l & 15) + 48);
        if (l < 16) ((unsigned*)(hb8 + (size_t)(nodeBase + n) * 64))[l] = pk8(v0, v1, v2, v3);
    }
}

__global__ __launch_bounds__(256) void scan1_kernel(const int* __restrict__ rowptr, int* __restrict__ bsum) {
    __shared__ int red[256];
    const int t = threadIdx.x, b = blockIdx.x;
    const int base = b * 1024;
    int s = 0;
    for (int i = t; i < 1024; i += 256) {
        const int idx = base + i;
        s += (idx < NN2) ? rowptr[idx] : 0;
    }
    red[t] = s;
    __syncthreads();
    for (int off = 128; off > 0; off >>= 1) {
        if (t < off) red[t] += red[t + off];
        __syncthreads();
    }
    if (t == 0) bsum[b] = red[0];
}

__global__ __launch_bounds__(256) void scan2_kernel(int* __restrict__ bsum) {
    __shared__ int s[256];
    const int t = threadIdx.x;
    const int v = (t < SCAN_B) ? bsum[t] : 0;
    s[t] = v;
    __syncthreads();
    for (int off = 1; off < 256; off <<= 1) {
        const int x = (t >= off) ? s[t - off] : 0;
        __syncthreads();
        s[t] += x;
        __syncthreads();
    }
    if (t < SCAN_B) bsum[t] = s[t] - v;  // exclusive
}

__global__ __launch_bounds__(256) void scan3_kernel(int* __restrict__ rowptr, const int* __restrict__ bsum,
                                                    float* __restrict__ deg) {
    __shared__ int red[256];
    const int t = threadIdx.x, b = blockIdx.x;
    const int i0 = b * 1024 + t * 4;
    int v[4];
#pragma unroll
    for (int j = 0; j < 4; ++j) v[j] = (i0 + j < NN2) ? rowptr[i0 + j] : 0;
    const int ts = v[0] + v[1] + v[2] + v[3];
    red[t] = ts;
    __syncthreads();
    for (int off = 1; off < 256; off <<= 1) {
        const int x = (t >= off) ? red[t - off] : 0;
        __syncthreads();
        red[t] += x;
        __syncthreads();
    }
    int pre = bsum[b] + red[t] - ts;
#pragma unroll
    for (int j = 0; j < 4; ++j) {
        if (i0 + j < NN2) {
            rowptr[i0 + j] = pre;
            deg[i0 + j] = (float)v[j];
            pre += v[j];
        }
    }
}

// ---- PARTITIONED fill (XCD-affine partition = blockIdx & 7) ----
__global__ __launch_bounds__(256) void fill_kernel(
    const int* __restrict__ adj0, const int* __restrict__ adj1,
    int* __restrict__ rowptr, int* __restrict__ csr) {
    const int part = blockIdx.x & 7;
    const int bid = blockIdx.x >> 3;
    const int lo = part * (NN2 / 8), hi = lo + NN2 / 8;
    for (int e = bid * 256 + threadIdx.x; e < 2 * NE; e += 64 * 256) {
        int2 st;
        int off;
        if (e < NE) {
            st = ((const int2*)adj0)[e];
            off = 0;
        } else {
            st = ((const int2*)adj1)[e - NE];
            off = NN;
        }
        const int tgt = st.y + off;
        if (tgt >= lo && tgt < hi) {
            const int pos = atomicAdd(&rowptr[tgt], 1);
            csr[pos] = st.x + off;
        }
    }
}

// ---- aggb[n] = bf16( sum over in-edges of fp8 hb8[src] ). 4 lanes x 16 B per node. ----
__global__ __launch_bounds__(256) void agg_kernel(
    const int* __restrict__ rowptr, const int* __restrict__ csr,
    const unsigned char* __restrict__ hb8, unsigned short* __restrict__ aggb) {
    const int t = threadIdx.x;
    const int node = blockIdx.x * 64 + (t >> 2);
    const int c = t & 3;
    const int start = node ? rowptr[node - 1] : 0;
    const int end = rowptr[node];
    float acc[16];
#pragma unroll
    for (int j = 0; j < 16; ++j) acc[j] = 0.f;
    int e = start;
    for (; e + 3 < end; e += 4) {
        int s[4];
        uint4 u[4];
#pragma unroll
        for (int q = 0; q < 4; ++q) s[q] = csr[e + q];
#pragma unroll
        for (int q = 0; q < 4; ++q) u[q] = *(const uint4*)(hb8 + (size_t)s[q] * 64 + c * 16);
#pragma unroll
        for (int q = 0; q < 4; ++q) {
            const f32x2 a0 = __builtin_amdgcn_cvt_pk_f32_fp8(u[q].x, false);
            const f32x2 a1 = __builtin_amdgcn_cvt_pk_f32_fp8(u[q].x, true);
            const f32x2 a2 = __builtin_amdgcn_cvt_pk_f32_fp8(u[q].y, false);
            const f32x2 a3 = __builtin_amdgcn_cvt_pk_f32_fp8(u[q].y, true);
            const f32x2 a4 = __builtin_amdgcn_cvt_pk_f32_fp8(u[q].z, false);
            const f32x2 a5 = __builtin_amdgcn_cvt_pk_f32_fp8(u[q].z, true);
            const f32x2 a6 = __builtin_amdgcn_cvt_pk_f32_fp8(u[q].w, false);
            const f32x2 a7 = __builtin_amdgcn_cvt_pk_f32_fp8(u[q].w, true);
            acc[0] += a0.x; acc[1] += a0.y; acc[2] += a1.x; acc[3] += a1.y;
            acc[4] += a2.x; acc[5] += a2.y; acc[6] += a3.x; acc[7] += a3.y;
            acc[8] += a4.x; acc[9] += a4.y; acc[10] += a5.x; acc[11] += a5.y;
            acc[12] += a6.x; acc[13] += a6.y; acc[14] += a7.x; acc[15] += a7.y;
        }
    }
    for (; e < end; ++e) {
        const uint4 u = *(const uint4*)(hb8 + (size_t)csr[e] * 64 + c * 16);
        const f32x2 a0 = __builtin_amdgcn_cvt_pk_f32_fp8(u.x, false);
        const f32x2 a1 = __builtin_amdgcn_cvt_pk_f32_fp8(u.x, true);
        const f32x2 a2 = __builtin_amdgcn_cvt_pk_f32_fp8(u.y, false);
        const f32x2 a3 = __builtin_amdgcn_cvt_pk_f32_fp8(u.y, true);
        const f32x2 a4 = __builtin_amdgcn_cvt_pk_f32_fp8(u.z, false);
        const f32x2 a5 = __builtin_amdgcn_cvt_pk_f32_fp8(u.z, true);
        const f32x2 a6 = __builtin_amdgcn_cvt_pk_f32_fp8(u.w, false);
        const f32x2 a7 = __builtin_amdgcn_cvt_pk_f32_fp8(u.w, true);
        acc[0] += a0.x; acc[1] += a0.y; acc[2] += a1.x; acc[3] += a1.y;
        acc[4] += a2.x; acc[5] += a2.y; acc[6] += a3.x; acc[7] += a3.y;
        acc[8] += a4.x; acc[9] += a4.y; acc[10] += a5.x; acc[11] += a5.y;
        acc[12] += a6.x; acc[13] += a6.y; acc[14] += a7.x; acc[15] += a7.y;
    }
    uint4 o0, o1;
    o0.x = packb(acc[0], acc[1]);
    o0.y = packb(acc[2], acc[3]);
    o0.z = packb(acc[4], acc[5]);
    o0.w = packb(acc[6], acc[7]);
    o1.x = packb(acc[8], acc[9]);
    o1.y = packb(acc[10], acc[11]);
    o1.z = packb(acc[12], acc[13]);
    o1.w = packb(acc[14], acc[15]);
    *(uint4*)(aggb + node * 64 + c * 16) = o0;
    *(uint4*)(aggb + node * 64 + c * 16 + 8) = o1;
}

// ---- aggX[p] for the 8192 (graph,b) prop pairs only ----
__global__ __launch_bounds__(256) void aggx_kernel(
    const int* __restrict__ prop0, const int* __restrict__ prop1,
    const int* __restrict__ rowptr, const int* __restrict__ csr,
    const unsigned char* __restrict__ hb8, unsigned short* __restrict__ aggX) {
    const int t = threadIdx.x;
    const int p = blockIdx.x * 64 + (t >> 2);
    const int c = t & 3;
    const int node = (p < BT) ? prop0[p] : NN + prop1[p - BT];
    const int start = node ? rowptr[node - 1] : 0;
    const int end = rowptr[node];
    float acc[16];
#pragma unroll
    for (int j = 0; j < 16; ++j) acc[j] = 0.f;
    for (int e = start; e < end; ++e) {
        const uint4 u = *(const uint4*)(hb8 + (size_t)csr[e] * 64 + c * 16);
        const f32x2 a0 = __builtin_amdgcn_cvt_pk_f32_fp8(u.x, false);
        const f32x2 a1 = __builtin_amdgcn_cvt_pk_f32_fp8(u.x, true);
        const f32x2 a2 = __builtin_amdgcn_cvt_pk_f32_fp8(u.y, false);
        const f32x2 a3 = __builtin_amdgcn_cvt_pk_f32_fp8(u.y, true);
        const f32x2 a4 = __builtin_amdgcn_cvt_pk_f32_fp8(u.z, false);
        const f32x2 a5 = __builtin_amdgcn_cvt_pk_f32_fp8(u.z, true);
        const f32x2 a6 = __builtin_amdgcn_cvt_pk_f32_fp8(u.w, false);
        const f32x2 a7 = __builtin_amdgcn_cvt_pk_f32_fp8(u.w, true);
        acc[0] += a0.x; acc[1] += a0.y; acc[2] += a1.x; acc[3] += a1.y;
        acc[4] += a2.x; acc[5] += a2.y; acc[6] += a3.x; acc[7] += a3.y;
        acc[8] += a4.x; acc[9] += a4.y; acc[10] += a5.x; acc[11] += a5.y;
        acc[12] += a6.x; acc[13] += a6.y; acc[14] += a7.x; acc[15] += a7.y;
    }
    uint4 o0, o1;
    o0.x = packb(acc[0], acc[1]);
    o0.y = packb(acc[2], acc[3]);
    o0.z = packb(acc[4], acc[5]);
    o0.w = packb(acc[6], acc[7]);
    o1.x = packb(acc[8], acc[9]);
    o1.y = packb(acc[10], acc[11]);
    o1.z = packb(acc[12], acc[13]);
    o1.w = packb(acc[14], acc[15]);
    *(uint4*)(aggX + p * 64 + c * 16) = o0;
    *(uint4*)(aggX + p * 64 + c * 16 + 8) = o1;
}

// ---- MFMA GRU: 512 thr (one 64 KB weight stage per CU), 2 M-tiles/wave, fp8 state ----
__global__ __launch_bounds__(512) void gru_mfma_kernel(
    unsigned char* __restrict__ hb8, const unsigned short* __restrict__ aggb,
    const float* __restrict__ deg, const unsigned short* __restrict__ Wpk,
    const float* __restrict__ bf, const float* __restrict__ bih, const float* __restrict__ bhh) {
    extern __shared__ unsigned short ldsW[];  // 64 KB
    {
        const uint4* src = (const uint4*)Wpk;
        uint4* dst = (uint4*)ldsW;
        for (int i = threadIdx.x; i < 4096; i += 512) dst[i] = src[i];
    }
    __syncthreads();
    const int lane = threadIdx.x & 63;
    const int j0 = lane & 15, quad = lane >> 4;
    const int q8 = quad * 8;
    float cr[4], cz[4], cig[4], chg[4], vbfr[4], vbfz[4], vbfg[4];
#pragma unroll
    for (int c4 = 0; c4 < 4; ++c4) {
        const int col = c4 * 16 + j0;
        cr[c4] = bih[col] + bhh[col];
        cz[c4] = bih[64 + col] + bhh[64 + col];
        cig[c4] = bih[128 + col];
        chg[c4] = bhh[128 + col];
        vbfr[c4] = bf[col];
        vbfz[c4] = bf[64 + col];
        vbfg[c4] = bf[128 + col];
    }
    const short8* ldsW8 = (const short8*)ldsW;
    const int gw = blockIdx.x * 8 + (threadIdx.x >> 6);
    const int nw = gridDim.x * 8;

    auto epilogue = [&](const f32x4(&acc)[16], int nb) {
#pragma unroll
        for (int reg = 0; reg < 4; ++reg) {
            const int node = nb + reg;
            const float dg = deg[node];
            const unsigned hu = *(const unsigned*)(hb8 + (size_t)node * 64 + j0 * 4);
            const f32x2 h01 = __builtin_amdgcn_cvt_pk_f32_fp8(hu, false);
            const f32x2 h23 = __builtin_amdgcn_cvt_pk_f32_fp8(hu, true);
            const float holdf[4] = {h01.x, h01.y, h23.x, h23.y};
            float hn[4];
#pragma unroll
            for (int c4 = 0; c4 < 4; ++c4) {
                const float rv = sig1(acc[c4][reg] + cr[c4] + dg * vbfr[c4]);
                const float zv = sig1(acc[4 + c4][reg] + cz[c4] + dg * vbfz[c4]);
                const float gi = acc[8 + c4][reg] + cig[c4] + dg * vbfg[c4];
                const float gh = acc[12 + c4][reg] + chg[c4];
                const float nv = tanh1(fmaf(rv, gh, gi));
                hn[c4] = (1.f - zv) * nv + zv * holdf[c4];
            }
            ((unsigned*)(hb8 + (size_t)node * 64))[j0] = pk8(hn[0], hn[1], hn[2], hn[3]);
        }
    };

    for (int t = gw; t < NN2 / 32; t += nw) {
        const int mbase = t * 32;
        const int node0 = mbase + j0, node1 = node0 + 16;
        short8 a[4], b[4];
        a[0] = *(const short8*)(aggb + node0 * 64 + q8);
        a[1] = *(const short8*)(aggb + node0 * 64 + 32 + q8);
        a[2] = f8frag(*(const uint2*)(hb8 + (size_t)node0 * 64 + q8));
        a[3] = f8frag(*(const uint2*)(hb8 + (size_t)node0 * 64 + 32 + q8));
        b[0] = *(const short8*)(aggb + node1 * 64 + q8);
        b[1] = *(const short8*)(aggb + node1 * 64 + 32 + q8);
        b[2] = f8frag(*(const uint2*)(hb8 + (size_t)node1 * 64 + q8));
        b[3] = f8frag(*(const uint2*)(hb8 + (size_t)node1 * 64 + 32 + q8));
        f32x4 acc0[16], acc1[16];
#pragma unroll
        for (int i = 0; i < 16; ++i) {
            acc0[i] = (f32x4){0.f, 0.f, 0.f, 0.f};
            acc1[i] = (f32x4){0.f, 0.f, 0.f, 0.f};
        }
#pragma unroll
        for (int nt = 0; nt < 16; ++nt) {
#pragma unroll
            for (int kk = 0; kk < 4; ++kk) {
                const short8 w = ldsW8[(nt * 4 + kk) * 64 + lane];
                acc0[nt] = __builtin_amdgcn_mfma_f32_16x16x32_bf16(a[kk], w, acc0[nt], 0, 0, 0);
                acc1[nt] = __builtin_amdgcn_mfma_f32_16x16x32_bf16(b[kk], w, acc1[nt], 0, 0, 0);
            }
        }
        epilogue(acc0, mbase + quad * 4);
        epilogue(acc1, mbase + 16 + quad * 4);
    }
}

// ---- Last-timestep GRU over the 8192 prop pairs only; writes X (fp32) directly. ----
__global__ __launch_bounds__(256) void grux_kernel(
    const int* __restrict__ prop0, const int* __restrict__ prop1,
    const unsigned char* __restrict__ hb8, const unsigned short* __restrict__ aggX,
    const float* __restrict__ deg, const unsigned short* __restrict__ Wpk,
    const float* __restrict__ bf, const float* __restrict__ bih, const float* __restrict__ bhh,
    float* __restrict__ X) {
    extern __shared__ unsigned short ldsW[];  // 64 KB
    {
        const uint4* src = (const uint4*)Wpk;
        uint4* dst = (uint4*)ldsW;
        for (int i = threadIdx.x; i < 4096; i += 256) dst[i] = src[i];
    }
    __syncthreads();
    const int lane = threadIdx.x & 63;
    const int j0 = lane & 15, quad = lane >> 4;
    const int q8 = quad * 8;
    float cr[4], cz[4], cig[4], chg[4], vbfr[4], vbfz[4], vbfg[4];
#pragma unroll
    for (int c4 = 0; c4 < 4; ++c4) {
        const int col = c4 * 16 + j0;
        cr[c4] = bih[col] + bhh[col];
        cz[c4] = bih[64 + col] + bhh[64 + col];
        cig[c4] = bih[128 + col];
        chg[c4] = bhh[128 + col];
        vbfr[c4] = bf[col];
        vbfz[c4] = bf[64 + col];
        vbfg[c4] = bf[128 + col];
    }
    const short8* ldsW8 = (const short8*)ldsW;
    const int gw = blockIdx.x * 4 + (threadIdx.x >> 6);  // 0..255, tile of 32 pairs

    auto mapnode = [&](int p) { return (p < BT) ? prop0[p] : NN + prop1[p - BT]; };

    auto epilogue = [&](const f32x4(&acc)[16], int pb) {
#pragma unroll
        for (int reg = 0; reg < 4; ++reg) {
            const int p = pb + reg;
            const int node = mapnode(p);
            const float dg = deg[node];
            const unsigned hu = *(const unsigned*)(hb8 + (size_t)node * 64 + j0 * 4);
            const f32x2 h01 = __builtin_amdgcn_cvt_pk_f32_fp8(hu, false);
            const f32x2 h23 = __builtin_amdgcn_cvt_pk_f32_fp8(hu, true);
            const float holdf[4] = {h01.x, h01.y, h23.x, h23.y};
            const int b = p & (BT - 1), g = p >> 12;
            float* xr = X + b * 128 + g * 64;
#pragma unroll
            for (int c4 = 0; c4 < 4; ++c4) {
                const int col = c4 * 16 + j0;
                const float rv = sig1(acc[c4][reg] + cr[c4] + dg * vbfr[c4]);
                const float zv = sig1(acc[4 + c4][reg] + cz[c4] + dg * vbfz[c4]);
                const float gi = acc[8 + c4][reg] + cig[c4] + dg * vbfg[c4];
                const float gh = acc[12 + c4][reg] + chg[c4];
                const float nv = tanh1(fmaf(rv, gh, gi));
                xr[col] = (1.f - zv) * nv + zv * holdf[c4];
            }
        }
    };

    const int mbase = gw * 32;
    const int p0 = mbase + j0, p1 = p0 + 16;
    const int node0 = mapnode(p0), node1 = mapnode(p1);
    short8 a[4], b[4];
    a[0] = *(const short8*)(aggX + p0 * 64 + q8);
    a[1] = *(const short8*)(aggX + p0 * 64 + 32 + q8);
    a[2] = f8frag(*(const uint2*)(hb8 + (size_t)node0 * 64 + q8));
    a[3] = f8frag(*(const uint2*)(hb8 + (size_t)node0 * 64 + 32 + q8));
    b[0] = *(const short8*)(aggX + p1 * 64 + q8);
    b[1] = *(const short8*)(aggX + p1 * 64 + 32 + q8);
    b[2] = f8frag(*(const uint2*)(hb8 + (size_t)node1 * 64 + q8));
    b[3] = f8frag(*(const uint2*)(hb8 + (size_t)node1 * 64 + 32 + q8));
    f32x4 acc0[16], acc1[16];
#pragma unroll
    for (int i = 0; i < 16; ++i) {
        acc0[i] = (f32x4){0.f, 0.f, 0.f, 0.f};
        acc1[i] = (f32x4){0.f, 0.f, 0.f, 0.f};
    }
#pragma unroll
    for (int nt = 0; nt < 16; ++nt) {
#pragma unroll
        for (int kk = 0; kk < 4; ++kk) {
            const short8 w = ldsW8[(nt * 4 + kk) * 64 + lane];
            acc0[nt] = __builtin_amdgcn_mfma_f32_16x16x32_bf16(a[kk], w, acc0[nt], 0, 0, 0);
            acc1[nt] = __builtin_amdgcn_mfma_f32_16x16x32_bf16(b[kk], w, acc1[nt], 0, 0, 0);
        }
    }
    epilogue(acc0, mbase + quad * 4);
    epilogue(acc1, mbase + 16 + quad * 4);
}

// ---- hidden = relu(X@W1+b1); z = hidden@W2+b2; out[b]=sigmoid(z); zbuf[b]=z ----
__global__ __launch_bounds__(256) void mlp_kernel(
    const float* __restrict__ X, const float* __restrict__ W1, const float* __restrict__ b1,
    const float* __restrict__ W2, const float* __restrict__ b2,
    float* __restrict__ out, float* __restrict__ zbuf) {
    const int b = blockIdx.x * 4 + (threadIdx.x >> 6);
    const int j = threadIdx.x & 63;
    const float* x = X + b * 128;
    float acc = b1[j];
#pragma unroll 4
    for (int k = 0; k < 128; ++k) acc = fmaf(x[k], W1[k * 64 + j], acc);
    float v = fmaxf(acc, 0.f) * W2[j];
#pragma unroll
    for (int off = 32; off > 0; off >>= 1) v += __shfl_down(v, off);
    if (j == 0) {
        const float z = v + b2[0];
        out[b] = 1.f / (1.f + expf(-z));
        zbuf[b] = z;
    }
}

// ---- loss = -mean(y*logsig(z) + (1-y)*logsig(-z)) -> out[BT] ----
__global__ __launch_bounds__(256) void loss_kernel(
    const float* __restrict__ zbuf, const int* __restrict__ labels, float* __restrict__ out) {
    __shared__ float red[256];
    const int t = threadIdx.x;
    float s = 0.f;
    for (int i = t; i < BT; i += 256) {
        const float z = zbuf[i];
        const float y = (float)labels[i];
        const float lsp = (z >= 0.f) ? -log1pf(expf(-z)) : (z - log1pf(expf(z)));
        const float lsn = lsp - z;
        s += y * lsp + (1.f - y) * lsn;
    }
    red[t] = s;
    __syncthreads();
    for (int off = 128; off > 0; off >>= 1) {
        if (t < off) red[t] += red[t + off];
        __syncthreads();
    }
    if (t == 0) out[BT] = -red[0] / (float)BT;
}

extern "C" void kernel_launch(void* const* d_in, const int* in_sizes, int n_in,
                              void* d_out, int out_size, void* d_ws, size_t ws_size,
                              hipStream_t stream) {
    char* ws = (char*)d_ws;
    unsigned short* aggb = (unsigned short*)(ws);             // 25,600,000 B  (NN2 rows)
    unsigned char* hb8 = (unsigned char*)(ws + 25600000);     // 12,800,000 B
    float* deg = (float*)(ws + 38400000);                     // 800,000 B
    float* Wf = (float*)(ws + 39200000);                      // 98,304 B
    float* bf = (float*)(ws + 39298304);                      // 1,536 B
    int* rowptr = (int*)(ws + 39299840);                      // 800,000 B
    int* csr = (int*)(ws + 40099840);                         // 9,600,000 B
    int* bsum = (int*)(ws + 49699840);                        // 1,024 B
    unsigned short* Wpk = (unsigned short*)(ws + 49700864);   // 131,072 B
    unsigned short* aggX = (unsigned short*)(ws + 49831936);  // 1,048,576 B
    // X/zbuf alias aggb (dead after last full gru; grux reads aggX + hb8 only).
    float* X = (float*)(ws);
    float* zbuf = (float*)(ws + 2097152);
    float* out = (float*)d_out;

    const float* emb_table = (const float*)d_in[7];
    const float* Wp = (const float*)d_in[8];
    const float* bp = (const float*)d_in[9];
    const int* prop0 = (const int*)d_in[4];
    const int* prop1 = (const int*)d_in[5];

    fusew_kernel<<<16, 256, 65536, stream>>>(
        (const float*)d_in[10], (const float*)d_in[12], (const float*)d_in[11],
        (const float*)d_in[16], (const float*)d_in[18], (const float*)d_in[17], Wf, bf);
    wpack_kernel<<<128, 64, 0, stream>>>(Wf, (const float*)d_in[13], (const float*)d_in[19], Wpk);

    // ---- CSR build; embed overlapped with hist in one dispatch ----
    hipMemsetAsync(rowptr, 0, (size_t)NN2 * 4, stream);
    histembed_kernel<<<HIST_B + EMB_B, 256, 0, stream>>>(
        (const int*)d_in[2], (const int*)d_in[3], rowptr,
        (const int*)d_in[0], (const int*)d_in[1], emb_table, Wp, bp, hb8);
    scan1_kernel<<<SCAN_B, 256, 0, stream>>>(rowptr, bsum);
    scan2_kernel<<<1, 256, 0, stream>>>(bsum);
    scan3_kernel<<<SCAN_B, 256, 0, stream>>>(rowptr, bsum, deg);
    fill_kernel<<<512, 256, 0, stream>>>((const int*)d_in[2], (const int*)d_in[3], rowptr, csr);

    // ---- batched GGNN chain; the very last timestep is pruned to the 8192 prop pairs ----
    for (int l = 0; l < 2; ++l) {
        const float* bih = (const float*)d_in[14 + 6 * l];
        const float* bhh = (const float*)d_in[15 + 6 * l];
        for (int ts = 0; ts < 3; ++ts) {
            if (l == 1 && ts == 2) {
                aggx_kernel<<<2 * BT / 64, 256, 0, stream>>>(prop0, prop1, rowptr, csr, hb8, aggX);
                grux_kernel<<<64, 256, 65536, stream>>>(prop0, prop1, hb8, aggX, deg,
                                                        Wpk + l * 32768, bf + l * 192, bih, bhh, X);
            } else {
                agg_kernel<<<NN2 / 64, 256, 0, stream>>>(rowptr, csr, hb8, aggb);
                gru_mfma_kernel<<<256, 512, 65536, stream>>>(hb8, aggb, deg, Wpk + l * 32768,
                                                             bf + l * 192, bih, bhh);
            }
        }
    }

    mlp_kernel<<<BT / 4, 256, 0, stream>>>(X, (const float*)d_in[22], (const float*)d_in[23],
                                           (const float*)d_in[24], (const float*)d_in[25], out, zbuf);
    loss_kernel<<<1, 256, 0, stream>>>(zbuf, (const int*)d_in[6], out);
}

// Round 23
// 960.247 us; speedup vs baseline: 1.3413x; 1.3413x over previous
//
#include <hip/hip_runtime.h>
#include <math.h>

#define NN 100000
#define NN2 200000
#define NE 1200000
#define EMBD 100
#define HD 64
#define BT 4096
#define SCAN_B 196  // 196 * 1024 >= NN2

typedef __attribute__((ext_vector_type(8))) short short8;  // 8 bf16 (4 VGPRs)
typedef __attribute__((ext_vector_type(4))) float f32x4;   // MFMA C/D
typedef __attribute__((ext_vector_type(2))) float f32x2;   // fp8 pk-cvt result

__device__ __forceinline__ float sig1(float x) { return 1.f / (1.f + __expf(-x)); }
__device__ __forceinline__ float tanh1(float x) {
    x = fminf(fmaxf(x, -15.f), 15.f);
    float e = __expf(2.f * x);
    return (e - 1.f) / (e + 1.f);
}
__device__ __forceinline__ unsigned short f2b(float f) {
    unsigned u = __float_as_uint(f);
    u += 0x7fffu + ((u >> 16) & 1u);
    return (unsigned short)(u >> 16);
}
__device__ __forceinline__ unsigned short hi16(float f) {  // exact for fp8-sourced values
    return (unsigned short)(__float_as_uint(f) >> 16);
}
__device__ __forceinline__ unsigned packb(float lo, float hi) {
    return (unsigned)f2b(lo) | ((unsigned)f2b(hi) << 16);
}
// PERMUTED row layout for hb8 (fp8 state) and aggb rows: position p holds feature
// (p&3)*16 + (p>>2); feature f lives at p = 4*(f&15) + (f>>4). Baked into wpack.
__device__ __forceinline__ unsigned pk8(float a, float b, float c, float d) {
    int w = 0;
    w = __builtin_amdgcn_cvt_pk_fp8_f32(a, b, w, false);
    w = __builtin_amdgcn_cvt_pk_fp8_f32(c, d, w, true);
    return (unsigned)w;
}
// 8 fp8 bytes -> 8 bf16 (exact: every e4m3 value is bf16-representable)
__device__ __forceinline__ short8 f8frag(uint2 u) {
    const f32x2 a0 = __builtin_amdgcn_cvt_pk_f32_fp8(u.x, false);
    const f32x2 a1 = __builtin_amdgcn_cvt_pk_f32_fp8(u.x, true);
    const f32x2 a2 = __builtin_amdgcn_cvt_pk_f32_fp8(u.y, false);
    const f32x2 a3 = __builtin_amdgcn_cvt_pk_f32_fp8(u.y, true);
    short8 r;
    r[0] = (short)hi16(a0.x); r[1] = (short)hi16(a0.y);
    r[2] = (short)hi16(a1.x); r[3] = (short)hi16(a1.y);
    r[4] = (short)hi16(a2.x); r[5] = (short)hi16(a2.y);
    r[6] = (short)hi16(a3.x); r[7] = (short)hi16(a3.y);
    return r;
}

// ---- precompute Wf[l] = Wm[l] @ Wih[l] (64x192), bf[l] = bm[l] @ Wih[l] (192) ----
__global__ __launch_bounds__(256) void fusew_kernel(
    const float* __restrict__ Wm0, const float* __restrict__ Wih0, const float* __restrict__ bm0,
    const float* __restrict__ Wm1, const float* __restrict__ Wih1, const float* __restrict__ bm1,
    float* __restrict__ Wf, float* __restrict__ bf) {
    extern __shared__ float lds[];
    float* wm_s = lds;          // 4096
    float* wih_s = lds + 4096;  // 12288
    const int l = blockIdx.x >> 3, slice = blockIdx.x & 7;
    const float* Wm = l ? Wm1 : Wm0;
    const float* Wih = l ? Wih1 : Wih0;
    const float* bm = l ? bm1 : bm0;
    for (int i = threadIdx.x; i < 4096; i += 256) wm_s[i] = Wm[i];
    for (int i = threadIdx.x; i < 12288; i += 256) wih_s[i] = Wih[i];
    __syncthreads();
    float* Wfl = Wf + l * 12288;
    float* bfl = bf + l * 192;
    const int o0 = slice * 1536;
    for (int o = o0 + threadIdx.x; o < o0 + 1536; o += 256) {
        int r = o / 192, c = o % 192;
        float s = 0.f;
        for (int k = 0; k < 64; ++k) s = fmaf(wm_s[r * 64 + k], wih_s[k * 192 + c], s);
        Wfl[o] = s;
    }
    const int c0 = slice * 24;
    for (int c = c0 + threadIdx.x; c < c0 + 24; c += 256) {
        float s = 0.f;
        for (int k = 0; k < 64; ++k) s = fmaf(bm[k], wih_s[k * 192 + c], s);
        bfl[c] = s;
    }
}

// ---- pack W' (128x256) into MFMA B-fragment order, bf16. Both halves permuted rows. ----
__global__ __launch_bounds__(64) void wpack_kernel(
    const float* __restrict__ Wf, const float* __restrict__ Whh0, const float* __restrict__ Whh1,
    unsigned short* __restrict__ Wpk) {
    const int b = blockIdx.x;  // 0..127
    const int l = b >> 6, frag = b & 63;
    const int nt = frag >> 2, kk = frag & 3;
    const int lane = threadIdx.x;
    const int n = nt * 16 + (lane & 15);
    const int g = n >> 6, j = n & 63;
    const int k0 = kk * 32 + (lane >> 4) * 8;
    const float* wf = Wf + l * 12288;
    const float* whh = l ? Whh1 : Whh0;
    unsigned short o[8];
#pragma unroll
    for (int jj = 0; jj < 8; ++jj) {
        const int k = k0 + jj;
        float v = 0.f;
        if (k < 64) {
            const int kp = (k & 3) * 16 + (k >> 2);
            if (g == 0) v = wf[kp * 192 + j];
            else if (g == 1) v = wf[kp * 192 + 64 + j];
            else if (g == 2) v = wf[kp * 192 + 128 + j];
        } else {
            const int kp = ((k - 64) & 3) * 16 + ((k - 64) >> 2);
            if (g == 0) v = whh[kp * 192 + j];
            else if (g == 1) v = whh[kp * 192 + 64 + j];
            else if (g == 3) v = whh[kp * 192 + 128 + j];
        }
        o[jj] = f2b(v);
    }
    *(uint4*)(Wpk + ((size_t)(l * 64 + frag) * 64 + lane) * 8) = *(const uint4*)o;
}

// ---- hb8[n] (fp8, permuted layout) for BOTH graphs in one dispatch ----
__global__ __launch_bounds__(256) void embed_kernel(
    const int* __restrict__ ind0, const int* __restrict__ ind1, const float* __restrict__ emb,
    const float* __restrict__ Wp, const float* __restrict__ bp,
    unsigned char* __restrict__ hb8) {
    __shared__ float et[4][EMBD][4];  // [wave][k][node]
    const int w = threadIdx.x >> 6;
    const int l = threadIdx.x & 63;
    const int nodeBase = blockIdx.x * 16 + w * 4;  // global node id (graph-pure per block)
    for (int f = l; f < 100; f += 64) {
        const int n = f / 25, c = f % 25;
        const int gn = nodeBase + n;
        const int idx = (gn < NN) ? ind0[gn] : ind1[gn - NN];
        const float4 v = *(const float4*)(emb + (size_t)idx * EMBD + c * 4);
        et[w][c * 4 + 0][n] = v.x;
        et[w][c * 4 + 1][n] = v.y;
        et[w][c * 4 + 2][n] = v.z;
        et[w][c * 4 + 3][n] = v.w;
    }
    __syncthreads();
    float acc[4];
    acc[0] = bp[l]; acc[1] = acc[0]; acc[2] = acc[0]; acc[3] = acc[0];
#pragma unroll 5
    for (int k = 0; k < EMBD; ++k) {
        const float wv = Wp[k * 64 + l];
        const float4 ev = *(const float4*)&et[w][k][0];
        acc[0] = fmaf(ev.x, wv, acc[0]);
        acc[1] = fmaf(ev.y, wv, acc[1]);
        acc[2] = fmaf(ev.z, wv, acc[2]);
        acc[3] = fmaf(ev.w, wv, acc[3]);
    }
#pragma unroll
    for (int n = 0; n < 4; ++n) {
        const float v0 = __shfl(acc[n], l & 15);
        const float v1 = __shfl(acc[n], (l & 15) + 16);
        const float v2 = __shfl(acc[n], (l & 15) + 32);
        const float v3 = __shfl(acc[n], (l & 15) + 48);
        if (l < 16) ((unsigned*)(hb8 + (size_t)(nodeBase + n) * 64))[l] = pk8(v0, v1, v2, v3);
    }
}

// ---- CSR build, both graphs in one dispatch (graph 1 offset +NN) ----
__global__ __launch_bounds__(256) void hist_kernel(
    const int* __restrict__ adj0, const int* __restrict__ adj1, int* __restrict__ rowptr) {
    const int e = blockIdx.x * 256 + threadIdx.x;
    const int tgt = (e < NE) ? adj0[2 * e + 1] : adj1[2 * (e - NE) + 1] + NN;
    atomicAdd(&rowptr[tgt], 1);
}

__global__ __launch_bounds__(256) void scan1_kernel(const int* __restrict__ rowptr, int* __restrict__ bsum) {
    __shared__ int red[256];
    const int t = threadIdx.x, b = blockIdx.x;
    const int base = b * 1024;
    int s = 0;
    for (int i = t; i < 1024; i += 256) {
        const int idx = base + i;
        s += (idx < NN2) ? rowptr[idx] : 0;
    }
    red[t] = s;
    __syncthreads();
    for (int off = 128; off > 0; off >>= 1) {
        if (t < off) red[t] += red[t + off];
        __syncthreads();
    }
    if (t == 0) bsum[b] = red[0];
}

__global__ __launch_bounds__(256) void scan2_kernel(int* __restrict__ bsum) {
    __shared__ int s[256];
    const int t = threadIdx.x;
    const int v = (t < SCAN_B) ? bsum[t] : 0;
    s[t] = v;
    __syncthreads();
    for (int off = 1; off < 256; off <<= 1) {
        const int x = (t >= off) ? s[t - off] : 0;
        __syncthreads();
        s[t] += x;
        __syncthreads();
    }
    if (t < SCAN_B) bsum[t] = s[t] - v;  // exclusive
}

__global__ __launch_bounds__(256) void scan3_kernel(int* __restrict__ rowptr, const int* __restrict__ bsum,
                                                    float* __restrict__ deg) {
    __shared__ int red[256];
    const int t = threadIdx.x, b = blockIdx.x;
    const int i0 = b * 1024 + t * 4;
    int v[4];
#pragma unroll
    for (int j = 0; j < 4; ++j) v[j] = (i0 + j < NN2) ? rowptr[i0 + j] : 0;
    const int ts = v[0] + v[1] + v[2] + v[3];
    red[t] = ts;
    __syncthreads();
    for (int off = 1; off < 256; off <<= 1) {
        const int x = (t >= off) ? red[t - off] : 0;
        __syncthreads();
        red[t] += x;
        __syncthreads();
    }
    int pre = bsum[b] + red[t] - ts;
#pragma unroll
    for (int j = 0; j < 4; ++j) {
        if (i0 + j < NN2) {
            rowptr[i0 + j] = pre;
            deg[i0 + j] = (float)v[j];
            pre += v[j];
        }
    }
}

// ---- PARTITIONED fill (XCD-affine partition = blockIdx & 7) ----
__global__ __launch_bounds__(256) void fill_kernel(
    const int* __restrict__ adj0, const int* __restrict__ adj1,
    int* __restrict__ rowptr, int* __restrict__ csr) {
    const int part = blockIdx.x & 7;
    const int bid = blockIdx.x >> 3;
    const int lo = part * (NN2 / 8), hi = lo + NN2 / 8;
    for (int e = bid * 256 + threadIdx.x; e < 2 * NE; e += 64 * 256) {
        int2 st;
        int off;
        if (e < NE) {
            st = ((const int2*)adj0)[e];
            off = 0;
        } else {
            st = ((const int2*)adj1)[e - NE];
            off = NN;
        }
        const int tgt = st.y + off;
        if (tgt >= lo && tgt < hi) {
            const int pos = atomicAdd(&rowptr[tgt], 1);
            csr[pos] = st.x + off;
        }
    }
}

// ---- aggb[n] = bf16( sum over in-edges of fp8 hb8[src] ). 4 lanes x 16 B per node. ----
__global__ __launch_bounds__(256) void agg_kernel(
    const int* __restrict__ rowptr, const int* __restrict__ csr,
    const unsigned char* __restrict__ hb8, unsigned short* __restrict__ aggb) {
    const int t = threadIdx.x;
    const int node = blockIdx.x * 64 + (t >> 2);
    const int c = t & 3;
    const int start = node ? rowptr[node - 1] : 0;
    const int end = rowptr[node];
    float acc[16];
#pragma unroll
    for (int j = 0; j < 16; ++j) acc[j] = 0.f;
    int e = start;
    for (; e + 3 < end; e += 4) {
        int s[4];
        uint4 u[4];
#pragma unroll
        for (int q = 0; q < 4; ++q) s[q] = csr[e + q];
#pragma unroll
        for (int q = 0; q < 4; ++q) u[q] = *(const uint4*)(hb8 + (size_t)s[q] * 64 + c * 16);
#pragma unroll
        for (int q = 0; q < 4; ++q) {
            const f32x2 a0 = __builtin_amdgcn_cvt_pk_f32_fp8(u[q].x, false);
            const f32x2 a1 = __builtin_amdgcn_cvt_pk_f32_fp8(u[q].x, true);
            const f32x2 a2 = __builtin_amdgcn_cvt_pk_f32_fp8(u[q].y, false);
            const f32x2 a3 = __builtin_amdgcn_cvt_pk_f32_fp8(u[q].y, true);
            const f32x2 a4 = __builtin_amdgcn_cvt_pk_f32_fp8(u[q].z, false);
            const f32x2 a5 = __builtin_amdgcn_cvt_pk_f32_fp8(u[q].z, true);
            const f32x2 a6 = __builtin_amdgcn_cvt_pk_f32_fp8(u[q].w, false);
            const f32x2 a7 = __builtin_amdgcn_cvt_pk_f32_fp8(u[q].w, true);
            acc[0] += a0.x; acc[1] += a0.y; acc[2] += a1.x; acc[3] += a1.y;
            acc[4] += a2.x; acc[5] += a2.y; acc[6] += a3.x; acc[7] += a3.y;
            acc[8] += a4.x; acc[9] += a4.y; acc[10] += a5.x; acc[11] += a5.y;
            acc[12] += a6.x; acc[13] += a6.y; acc[14] += a7.x; acc[15] += a7.y;
        }
    }
    for (; e < end; ++e) {
        const uint4 u = *(const uint4*)(hb8 + (size_t)csr[e] * 64 + c * 16);
        const f32x2 a0 = __builtin_amdgcn_cvt_pk_f32_fp8(u.x, false);
        const f32x2 a1 = __builtin_amdgcn_cvt_pk_f32_fp8(u.x, true);
        const f32x2 a2 = __builtin_amdgcn_cvt_pk_f32_fp8(u.y, false);
        const f32x2 a3 = __builtin_amdgcn_cvt_pk_f32_fp8(u.y, true);
        const f32x2 a4 = __builtin_amdgcn_cvt_pk_f32_fp8(u.z, false);
        const f32x2 a5 = __builtin_amdgcn_cvt_pk_f32_fp8(u.z, true);
        const f32x2 a6 = __builtin_amdgcn_cvt_pk_f32_fp8(u.w, false);
        const f32x2 a7 = __builtin_amdgcn_cvt_pk_f32_fp8(u.w, true);
        acc[0] += a0.x; acc[1] += a0.y; acc[2] += a1.x; acc[3] += a1.y;
        acc[4] += a2.x; acc[5] += a2.y; acc[6] += a3.x; acc[7] += a3.y;
        acc[8] += a4.x; acc[9] += a4.y; acc[10] += a5.x; acc[11] += a5.y;
        acc[12] += a6.x; acc[13] += a6.y; acc[14] += a7.x; acc[15] += a7.y;
    }
    uint4 o0, o1;
    o0.x = packb(acc[0], acc[1]);
    o0.y = packb(acc[2], acc[3]);
    o0.z = packb(acc[4], acc[5]);
    o0.w = packb(acc[6], acc[7]);
    o1.x = packb(acc[8], acc[9]);
    o1.y = packb(acc[10], acc[11]);
    o1.z = packb(acc[12], acc[13]);
    o1.w = packb(acc[14], acc[15]);
    *(uint4*)(aggb + node * 64 + c * 16) = o0;
    *(uint4*)(aggb + node * 64 + c * 16 + 8) = o1;
}

// ---- aggX[p] for the 8192 (graph,b) prop pairs only ----
__global__ __launch_bounds__(256) void aggx_kernel(
    const int* __restrict__ prop0, const int* __restrict__ prop1,
    const int* __restrict__ rowptr, const int* __restrict__ csr,
    const unsigned char* __restrict__ hb8, unsigned short* __restrict__ aggX) {
    const int t = threadIdx.x;
    const int p = blockIdx.x * 64 + (t >> 2);
    const int c = t & 3;
    const int node = (p < BT) ? prop0[p] : NN + prop1[p - BT];
    const int start = node ? rowptr[node - 1] : 0;
    const int end = rowptr[node];
    float acc[16];
#pragma unroll
    for (int j = 0; j < 16; ++j) acc[j] = 0.f;
    for (int e = start; e < end; ++e) {
        const uint4 u = *(const uint4*)(hb8 + (size_t)csr[e] * 64 + c * 16);
        const f32x2 a0 = __builtin_amdgcn_cvt_pk_f32_fp8(u.x, false);
        const f32x2 a1 = __builtin_amdgcn_cvt_pk_f32_fp8(u.x, true);
        const f32x2 a2 = __builtin_amdgcn_cvt_pk_f32_fp8(u.y, false);
        const f32x2 a3 = __builtin_amdgcn_cvt_pk_f32_fp8(u.y, true);
        const f32x2 a4 = __builtin_amdgcn_cvt_pk_f32_fp8(u.z, false);
        const f32x2 a5 = __builtin_amdgcn_cvt_pk_f32_fp8(u.z, true);
        const f32x2 a6 = __builtin_amdgcn_cvt_pk_f32_fp8(u.w, false);
        const f32x2 a7 = __builtin_amdgcn_cvt_pk_f32_fp8(u.w, true);
        acc[0] += a0.x; acc[1] += a0.y; acc[2] += a1.x; acc[3] += a1.y;
        acc[4] += a2.x; acc[5] += a2.y; acc[6] += a3.x; acc[7] += a3.y;
        acc[8] += a4.x; acc[9] += a4.y; acc[10] += a5.x; acc[11] += a5.y;
        acc[12] += a6.x; acc[13] += a6.y; acc[14] += a7.x; acc[15] += a7.y;
    }
    uint4 o0, o1;
    o0.x = packb(acc[0], acc[1]);
    o0.y = packb(acc[2], acc[3]);
    o0.z = packb(acc[4], acc[5]);
    o0.w = packb(acc[6], acc[7]);
    o1.x = packb(acc[8], acc[9]);
    o1.y = packb(acc[10], acc[11]);
    o1.z = packb(acc[12], acc[13]);
    o1.w = packb(acc[14], acc[15]);
    *(uint4*)(aggX + p * 64 + c * 16) = o0;
    *(uint4*)(aggX + p * 64 + c * 16 + 8) = o1;
}

// ---- MFMA GRU (full graph): 256 thr, 2 M-tiles/wave, ALL-FP8 STATE.
// NOTE: only clean at 256 thr (232 VGPR, zero spills) — 512 thr caps VGPR=128 and spills.
__global__ __launch_bounds__(256) void gru_mfma_kernel(
    unsigned char* __restrict__ hb8, const unsigned short* __restrict__ aggb,
    const float* __restrict__ deg, const unsigned short* __restrict__ Wpk,
    const float* __restrict__ bf, const float* __restrict__ bih, const float* __restrict__ bhh) {
    extern __shared__ unsigned short ldsW[];  // 64 KB
    {
        const uint4* src = (const uint4*)Wpk;
        uint4* dst = (uint4*)ldsW;
        for (int i = threadIdx.x; i < 4096; i += 256) dst[i] = src[i];
    }
    __syncthreads();
    const int lane = threadIdx.x & 63;
    const int j0 = lane & 15, quad = lane >> 4;
    const int q8 = quad * 8;
    float cr[4], cz[4], cig[4], chg[4], vbfr[4], vbfz[4], vbfg[4];
#pragma unroll
    for (int c4 = 0; c4 < 4; ++c4) {
        const int col = c4 * 16 + j0;
        cr[c4] = bih[col] + bhh[col];
        cz[c4] = bih[64 + col] + bhh[64 + col];
        cig[c4] = bih[128 + col];
        chg[c4] = bhh[128 + col];
        vbfr[c4] = bf[col];
        vbfz[c4] = bf[64 + col];
        vbfg[c4] = bf[128 + col];
    }
    const short8* ldsW8 = (const short8*)ldsW;
    const int gw = blockIdx.x * 4 + (threadIdx.x >> 6);
    const int nw = gridDim.x * 4;

    auto epilogue = [&](const f32x4(&acc)[16], int nb) {
#pragma unroll
        for (int reg = 0; reg < 4; ++reg) {
            const int node = nb + reg;
            const float dg = deg[node];
            const unsigned hu = *(const unsigned*)(hb8 + (size_t)node * 64 + j0 * 4);
            const f32x2 h01 = __builtin_amdgcn_cvt_pk_f32_fp8(hu, false);
            const f32x2 h23 = __builtin_amdgcn_cvt_pk_f32_fp8(hu, true);
            const float holdf[4] = {h01.x, h01.y, h23.x, h23.y};
            float hn[4];
#pragma unroll
            for (int c4 = 0; c4 < 4; ++c4) {
                const float rv = sig1(acc[c4][reg] + cr[c4] + dg * vbfr[c4]);
                const float zv = sig1(acc[4 + c4][reg] + cz[c4] + dg * vbfz[c4]);
                const float gi = acc[8 + c4][reg] + cig[c4] + dg * vbfg[c4];
                const float gh = acc[12 + c4][reg] + chg[c4];
                const float nv = tanh1(fmaf(rv, gh, gi));
                hn[c4] = (1.f - zv) * nv + zv * holdf[c4];
            }
            ((unsigned*)(hb8 + (size_t)node * 64))[j0] = pk8(hn[0], hn[1], hn[2], hn[3]);
        }
    };

    for (int t = gw; t < NN2 / 32; t += nw) {
        const int mbase = t * 32;
        const int node0 = mbase + j0, node1 = node0 + 16;
        short8 a[4], b[4];
        a[0] = *(const short8*)(aggb + node0 * 64 + q8);
        a[1] = *(const short8*)(aggb + node0 * 64 + 32 + q8);
        a[2] = f8frag(*(const uint2*)(hb8 + (size_t)node0 * 64 + q8));
        a[3] = f8frag(*(const uint2*)(hb8 + (size_t)node0 * 64 + 32 + q8));
        b[0] = *(const short8*)(aggb + node1 * 64 + q8);
        b[1] = *(const short8*)(aggb + node1 * 64 + 32 + q8);
        b[2] = f8frag(*(const uint2*)(hb8 + (size_t)node1 * 64 + q8));
        b[3] = f8frag(*(const uint2*)(hb8 + (size_t)node1 * 64 + 32 + q8));
        f32x4 acc0[16], acc1[16];
#pragma unroll
        for (int i = 0; i < 16; ++i) {
            acc0[i] = (f32x4){0.f, 0.f, 0.f, 0.f};
            acc1[i] = (f32x4){0.f, 0.f, 0.f, 0.f};
        }
#pragma unroll
        for (int nt = 0; nt < 16; ++nt) {
#pragma unroll
            for (int kk = 0; kk < 4; ++kk) {
                const short8 w = ldsW8[(nt * 4 + kk) * 64 + lane];
                acc0[nt] = __builtin_amdgcn_mfma_f32_16x16x32_bf16(a[kk], w, acc0[nt], 0, 0, 0);
                acc1[nt] = __builtin_amdgcn_mfma_f32_16x16x32_bf16(b[kk], w, acc1[nt], 0, 0, 0);
            }
        }
        epilogue(acc0, mbase + quad * 4);
        epilogue(acc1, mbase + 16 + quad * 4);
    }
}

// ---- Last-timestep GRU over the 8192 prop pairs only; writes X (fp32) directly. ----
__global__ __launch_bounds__(256) void grux_kernel(
    const int* __restrict__ prop0, const int* __restrict__ prop1,
    const unsigned char* __restrict__ hb8, const unsigned short* __restrict__ aggX,
    const float* __restrict__ deg, const unsigned short* __restrict__ Wpk,
    const float* __restrict__ bf, const float* __restrict__ bih, const float* __restrict__ bhh,
    float* __restrict__ X) {
    extern __shared__ unsigned short ldsW[];  // 64 KB
    {
        const uint4* src = (const uint4*)Wpk;
        uint4* dst = (uint4*)ldsW;
        for (int i = threadIdx.x; i < 4096; i += 256) dst[i] = src[i];
    }
    __syncthreads();
    const int lane = threadIdx.x & 63;
    const int j0 = lane & 15, quad = lane >> 4;
    const int q8 = quad * 8;
    float cr[4], cz[4], cig[4], chg[4], vbfr[4], vbfz[4], vbfg[4];
#pragma unroll
    for (int c4 = 0; c4 < 4; ++c4) {
        const int col = c4 * 16 + j0;
        cr[c4] = bih[col] + bhh[col];
        cz[c4] = bih[64 + col] + bhh[64 + col];
        cig[c4] = bih[128 + col];
        chg[c4] = bhh[128 + col];
        vbfr[c4] = bf[col];
        vbfz[c4] = bf[64 + col];
        vbfg[c4] = bf[128 + col];
    }
    const short8* ldsW8 = (const short8*)ldsW;
    const int gw = blockIdx.x * 4 + (threadIdx.x >> 6);  // 0..255, tile of 32 pairs

    auto mapnode = [&](int p) { return (p < BT) ? prop0[p] : NN + prop1[p - BT]; };

    auto epilogue = [&](const f32x4(&acc)[16], int pb) {
#pragma unroll
        for (int reg = 0; reg < 4; ++reg) {
            const int p = pb + reg;
            const int node = mapnode(p);
            const float dg = deg[node];
            const unsigned hu = *(const unsigned*)(hb8 + (size_t)node * 64 + j0 * 4);
            const f32x2 h01 = __builtin_amdgcn_cvt_pk_f32_fp8(hu, false);
            const f32x2 h23 = __builtin_amdgcn_cvt_pk_f32_fp8(hu, true);
            const float holdf[4] = {h01.x, h01.y, h23.x, h23.y};
            const int b = p & (BT - 1), g = p >> 12;
            float* xr = X + b * 128 + g * 64;
#pragma unroll
            for (int c4 = 0; c4 < 4; ++c4) {
                const int col = c4 * 16 + j0;
                const float rv = sig1(acc[c4][reg] + cr[c4] + dg * vbfr[c4]);
                const float zv = sig1(acc[4 + c4][reg] + cz[c4] + dg * vbfz[c4]);
                const float gi = acc[8 + c4][reg] + cig[c4] + dg * vbfg[c4];
                const float gh = acc[12 + c4][reg] + chg[c4];
                const float nv = tanh1(fmaf(rv, gh, gi));
                xr[col] = (1.f - zv) * nv + zv * holdf[c4];
            }
        }
    };

    const int mbase = gw * 32;
    const int p0 = mbase + j0, p1 = p0 + 16;
    const int node0 = mapnode(p0), node1 = mapnode(p1);
    short8 a[4], b[4];
    a[0] = *(const short8*)(aggX + p0 * 64 + q8);
    a[1] = *(const short8*)(aggX + p0 * 64 + 32 + q8);
    a[2] = f8frag(*(const uint2*)(hb8 + (size_t)node0 * 64 + q8));
    a[3] = f8frag(*(const uint2*)(hb8 + (size_t)node0 * 64 + 32 + q8));
    b[0] = *(const short8*)(aggX + p1 * 64 + q8);
    b[1] = *(const short8*)(aggX + p1 * 64 + 32 + q8);
    b[2] = f8frag(*(const uint2*)(hb8 + (size_t)node1 * 64 + q8));
    b[3] = f8frag(*(const uint2*)(hb8 + (size_t)node1 * 64 + 32 + q8));
    f32x4 acc0[16], acc1[16];
#pragma unroll
    for (int i = 0; i < 16; ++i) {
        acc0[i] = (f32x4){0.f, 0.f, 0.f, 0.f};
        acc1[i] = (f32x4){0.f, 0.f, 0.f, 0.f};
    }
#pragma unroll
    for (int nt = 0; nt < 16; ++nt) {
#pragma unroll
        for (int kk = 0; kk < 4; ++kk) {
            const short8 w = ldsW8[(nt * 4 + kk) * 64 + lane];
            acc0[nt] = __builtin_amdgcn_mfma_f32_16x16x32_bf16(a[kk], w, acc0[nt], 0, 0, 0);
            acc1[nt] = __builtin_amdgcn_mfma_f32_16x16x32_bf16(b[kk], w, acc1[nt], 0, 0, 0);
        }
    }
    epilogue(acc0, mbase + quad * 4);
    epilogue(acc1, mbase + 16 + quad * 4);
}

// ---- hidden = relu(X@W1+b1); z = hidden@W2+b2; out[b]=sigmoid(z); zbuf[b]=z ----
__global__ __launch_bounds__(256) void mlp_kernel(
    const float* __restrict__ X, const float* __restrict__ W1, const float* __restrict__ b1,
    const float* __restrict__ W2, const float* __restrict__ b2,
    float* __restrict__ out, float* __restrict__ zbuf) {
    const int b = blockIdx.x * 4 + (threadIdx.x >> 6);
    const int j = threadIdx.x & 63;
    const float* x = X + b * 128;
    float acc = b1[j];
#pragma unroll 4
    for (int k = 0; k < 128; ++k) acc = fmaf(x[k], W1[k * 64 + j], acc);
    float v = fmaxf(acc, 0.f) * W2[j];
#pragma unroll
    for (int off = 32; off > 0; off >>= 1) v += __shfl_down(v, off);
    if (j == 0) {
        const float z = v + b2[0];
        out[b] = 1.f / (1.f + expf(-z));
        zbuf[b] = z;
    }
}

// ---- loss = -mean(y*logsig(z) + (1-y)*logsig(-z)) -> out[BT] ----
__global__ __launch_bounds__(256) void loss_kernel(
    const float* __restrict__ zbuf, const int* __restrict__ labels, float* __restrict__ out) {
    __shared__ float red[256];
    const int t = threadIdx.x;
    float s = 0.f;
    for (int i = t; i < BT; i += 256) {
        const float z = zbuf[i];
        const float y = (float)labels[i];
        const float lsp = (z >= 0.f) ? -log1pf(expf(-z)) : (z - log1pf(expf(z)));
        const float lsn = lsp - z;
        s += y * lsp + (1.f - y) * lsn;
    }
    red[t] = s;
    __syncthreads();
    for (int off = 128; off > 0; off >>= 1) {
        if (t < off) red[t] += red[t + off];
        __syncthreads();
    }
    if (t == 0) out[BT] = -red[0] / (float)BT;
}

extern "C" void kernel_launch(void* const* d_in, const int* in_sizes, int n_in,
                              void* d_out, int out_size, void* d_ws, size_t ws_size,
                              hipStream_t stream) {
    char* ws = (char*)d_ws;
    unsigned short* aggb = (unsigned short*)(ws);             // 25,600,000 B  (NN2 rows)
    unsigned char* hb8 = (unsigned char*)(ws + 25600000);     // 12,800,000 B
    float* deg = (float*)(ws + 38400000);                     // 800,000 B
    float* Wf = (float*)(ws + 39200000);                      // 98,304 B
    float* bf = (float*)(ws + 39298304);                      // 1,536 B
    int* rowptr = (int*)(ws + 39299840);                      // 800,000 B
    int* csr = (int*)(ws + 40099840);                         // 9,600,000 B
    int* bsum = (int*)(ws + 49699840);                        // 1,024 B
    unsigned short* Wpk = (unsigned short*)(ws + 49700864);   // 131,072 B
    unsigned short* aggX = (unsigned short*)(ws + 49831936);  // 1,048,576 B
    // X/zbuf alias aggb (dead after last full gru; grux reads aggX + hb8 only).
    float* X = (float*)(ws);
    float* zbuf = (float*)(ws + 2097152);
    float* out = (float*)d_out;

    const float* emb_table = (const float*)d_in[7];
    const float* Wp = (const float*)d_in[8];
    const float* bp = (const float*)d_in[9];
    const int* prop0 = (const int*)d_in[4];
    const int* prop1 = (const int*)d_in[5];

    fusew_kernel<<<16, 256, 65536, stream>>>(
        (const float*)d_in[10], (const float*)d_in[12], (const float*)d_in[11],
        (const float*)d_in[16], (const float*)d_in[18], (const float*)d_in[17], Wf, bf);
    wpack_kernel<<<128, 64, 0, stream>>>(Wf, (const float*)d_in[13], (const float*)d_in[19], Wpk);

    // ---- combined CSR build ----
    hipMemsetAsync(rowptr, 0, (size_t)NN2 * 4, stream);
    hist_kernel<<<2 * NE / 256, 256, 0, stream>>>((const int*)d_in[2], (const int*)d_in[3], rowptr);
    scan1_kernel<<<SCAN_B, 256, 0, stream>>>(rowptr, bsum);
    scan2_kernel<<<1, 256, 0, stream>>>(bsum);
    scan3_kernel<<<SCAN_B, 256, 0, stream>>>(rowptr, bsum, deg);
    fill_kernel<<<512, 256, 0, stream>>>((const int*)d_in[2], (const int*)d_in[3], rowptr, csr);

    // ---- embeddings, both graphs in one dispatch ----
    embed_kernel<<<NN2 / 16, 256, 0, stream>>>((const int*)d_in[0], (const int*)d_in[1], emb_table,
                                               Wp, bp, hb8);

    // ---- batched GGNN chain; the very last timestep is pruned to the 8192 prop pairs ----
    for (int l = 0; l < 2; ++l) {
        const float* bih = (const float*)d_in[14 + 6 * l];
        const float* bhh = (const float*)d_in[15 + 6 * l];
        for (int ts = 0; ts < 3; ++ts) {
            if (l == 1 && ts == 2) {
                aggx_kernel<<<2 * BT / 64, 256, 0, stream>>>(prop0, prop1, rowptr, csr, hb8, aggX);
                grux_kernel<<<64, 256, 65536, stream>>>(prop0, prop1, hb8, aggX, deg,
                                                        Wpk + l * 32768, bf + l * 192, bih, bhh, X);
            } else {
                agg_kernel<<<NN2 / 64, 256, 0, stream>>>(rowptr, csr, hb8, aggb);
                gru_mfma_kernel<<<512, 256, 65536, stream>>>(hb8, aggb, deg, Wpk + l * 32768,
                                                             bf + l * 192, bih, bhh);
            }
        }
    }

    mlp_kernel<<<BT / 4, 256, 0, stream>>>(X, (const float*)d_in[22], (const float*)d_in[23],
                                           (const float*)d_in[24], (const float*)d_in[25], out, zbuf);
    loss_kernel<<<1, 256, 0, stream>>>(zbuf, (const int*)d_in[6], out);
}